// Round 1
// baseline (43277.148 us; speedup 1.0000x reference)
//
#include <hip/hip_runtime.h>
#include <math.h>

typedef float f4 __attribute__((ext_vector_type(4)));

// ---------------- workspace layout (float offsets) ----------------
// At  : A transposed [j][i]            1,000,000
// AX  : A@x for all t [i][t*128+b*2+c] 6,144,000
// H0,C0,H1,C1 : [j][b*64+h]            4 x 4,096,000
// AH_a, AH_b  : GEMM outputs           2 x 4,096,000
// Xr (transposed x) aliases AH_a/AH_b region (only used before T loop)
#define WS_AT   0
#define WS_AX   1000000
#define WS_H0   7144000
#define WS_C0   11240000
#define WS_H1   15336000
#define WS_C1   19432000
#define WS_AHA  23528000
#define WS_AHB  27624000

// ---------------- A = softmax(relu(E1 @ E2^T)) in fp64, store A^T ----------------
__global__ __launch_bounds__(256) void compute_A(const float* __restrict__ E1,
                                                 const float* __restrict__ E2,
                                                 float* __restrict__ At)
{
    __shared__ double z[1000];
    __shared__ double red[256];
    __shared__ double e1[16];
    const int i = blockIdx.x;
    const int tid = threadIdx.x;
    if (tid < 16) e1[tid] = (double)E1[i * 16 + tid];
    __syncthreads();
    double lmax = -1e300;
    for (int j = tid; j < 1000; j += 256) {
        double s = 0.0;
        #pragma unroll
        for (int c = 0; c < 16; ++c) s += e1[c] * (double)E2[j * 16 + c];
        if (s < 0.0) s = 0.0;              // relu
        z[j] = s;
        if (s > lmax) lmax = s;
    }
    red[tid] = lmax; __syncthreads();
    for (int off = 128; off > 0; off >>= 1) {
        if (tid < off) red[tid] = fmax(red[tid], red[tid + off]);
        __syncthreads();
    }
    const double zmax = red[0];
    __syncthreads();
    double lsum = 0.0;
    for (int j = tid; j < 1000; j += 256) {
        double e = exp(z[j] - zmax);
        z[j] = e;
        lsum += e;
    }
    red[tid] = lsum; __syncthreads();
    for (int off = 128; off > 0; off >>= 1) {
        if (tid < off) red[tid] += red[tid + off];
        __syncthreads();
    }
    const double inv = 1.0 / red[0];
    for (int j = tid; j < 1000; j += 256)
        At[(size_t)j * 1000 + i] = (float)(z[j] * inv);   // store transposed
}

// ---------------- x [B,T,N,C] -> Xr [j][t*128 + b*2 + c] ----------------
__global__ __launch_bounds__(256) void transpose_x(const float* __restrict__ x,
                                                   float* __restrict__ Xr)
{
    int o = blockIdx.x * 256 + threadIdx.x;
    if (o >= 6144000) return;
    int j = o / 6144;
    int r = o - j * 6144;
    int t = r >> 7;
    int q = r & 127;
    int b = q >> 1;
    int c = q & 1;
    Xr[o] = x[(((size_t)(b * 48 + t)) * 1000 + j) * 2 + c];
}

// ---------------- zero fill ----------------
__global__ __launch_bounds__(256) void zero_kernel(float* __restrict__ p, int n4)
{
    int i = blockIdx.x * 256 + threadIdx.x;
    if (i < n4) { f4 z = {0.f, 0.f, 0.f, 0.f}; ((f4*)p)[i] = z; }
}

// ---------------- C[1000][ncols] = A @ B ; A given transposed At[k][1000] ----------------
// BM=64 BN=128 BK=8, 256 threads, 4x8 micro-tile
__global__ __launch_bounds__(256) void gemm1000(const float* __restrict__ At,
                                                const float* __restrict__ B,
                                                float* __restrict__ C,
                                                int ncols)
{
    __shared__ float As[8][64];
    __shared__ float Bs[8][128];
    const int tid = threadIdx.x;
    const int tx = tid & 15;          // col group: cols tx*8 .. +7
    const int ty = tid >> 4;          // row group: rows ty*4 .. +3
    const int row0 = blockIdx.x * 64;
    const int col0 = blockIdx.y * 128;

    const int lm = tid & 63;
    const int lk = tid >> 6;          // 0..3  (k = lk, lk+4)
    const int bcol = tid & 127;
    const int bk = tid >> 7;          // 0..1  (k = bk*4 + kk)
    const bool arow_ok = (row0 + lm) < 1000;

    float acc[4][8];
    #pragma unroll
    for (int r = 0; r < 4; ++r)
        #pragma unroll
        for (int c = 0; c < 8; ++c) acc[r][c] = 0.f;

    for (int k0 = 0; k0 < 1000; k0 += 8) {
        float a0 = arow_ok ? At[(size_t)(k0 + lk) * 1000 + row0 + lm] : 0.f;
        float a1 = arow_ok ? At[(size_t)(k0 + lk + 4) * 1000 + row0 + lm] : 0.f;
        float bv[4];
        #pragma unroll
        for (int kk = 0; kk < 4; ++kk)
            bv[kk] = B[(size_t)(k0 + bk * 4 + kk) * ncols + col0 + bcol];
        __syncthreads();
        As[lk][lm] = a0;
        As[lk + 4][lm] = a1;
        #pragma unroll
        for (int kk = 0; kk < 4; ++kk) Bs[bk * 4 + kk][bcol] = bv[kk];
        __syncthreads();
        #pragma unroll
        for (int k = 0; k < 8; ++k) {
            f4 av = *(const f4*)&As[k][ty * 4];
            f4 b0 = *(const f4*)&Bs[k][tx * 8];
            f4 b1 = *(const f4*)&Bs[k][tx * 8 + 4];
            #pragma unroll
            for (int r = 0; r < 4; ++r) {
                float a = av[r];
                acc[r][0] = fmaf(a, b0[0], acc[r][0]);
                acc[r][1] = fmaf(a, b0[1], acc[r][1]);
                acc[r][2] = fmaf(a, b0[2], acc[r][2]);
                acc[r][3] = fmaf(a, b0[3], acc[r][3]);
                acc[r][4] = fmaf(a, b1[0], acc[r][4]);
                acc[r][5] = fmaf(a, b1[1], acc[r][5]);
                acc[r][6] = fmaf(a, b1[2], acc[r][6]);
                acc[r][7] = fmaf(a, b1[3], acc[r][7]);
            }
        }
    }
    #pragma unroll
    for (int r = 0; r < 4; ++r) {
        int row = row0 + ty * 4 + r;
        if (row < 1000) {
            f4 o0 = {acc[r][0], acc[r][1], acc[r][2], acc[r][3]};
            f4 o1 = {acc[r][4], acc[r][5], acc[r][6], acc[r][7]};
            *(f4*)&C[(size_t)row * ncols + col0 + tx * 8]     = o0;
            *(f4*)&C[(size_t)row * ncols + col0 + tx * 8 + 4] = o1;
        }
    }
}

// ---------------- fused gate GEMM (K=64 [x2]) + LSTM pointwise ----------------
// rows r = i*64+b of AH [64000][64]; 16 rows/block; thread: 4 rows x 4 gates at h=tx
__global__ __launch_bounds__(256) void gates_kernel(
    const float* __restrict__ AHh, const float* __restrict__ Wh, const float* __restrict__ bh,
    const float* __restrict__ AHx, const float* __restrict__ Wxg, const float* __restrict__ bxg,
    const float* __restrict__ Ax,  const float* __restrict__ Wx2, const float* __restrict__ bx2,
    int t,
    float* __restrict__ Cst, float* __restrict__ Hout)
{
    __shared__ float As[64][20];      // [k][m], padded stride 20 (16B-aligned rows)
    const int tid = threadIdx.x;
    const int tx = tid & 63;          // h index
    const int ty = tid >> 6;          // 0..3
    const int row0 = blockIdx.x * 16;

    float acc[4][4];                  // [row][gate]
    #pragma unroll
    for (int r = 0; r < 4; ++r)
        #pragma unroll
        for (int g = 0; g < 4; ++g) acc[r][g] = 0.f;

    const float* Ap = AHh;
    const float* Wp = Wh;
    for (int pass = 0; pass < 2; ++pass) {
        if (pass == 1) { if (!AHx) break; Ap = AHx; Wp = Wxg; }
        __syncthreads();
        #pragma unroll
        for (int q = 0; q < 4; ++q) {
            int m = q * 4 + ty;
            As[tx][m] = Ap[(size_t)(row0 + m) * 64 + tx];
        }
        __syncthreads();
        #pragma unroll
        for (int kc = 0; kc < 16; ++kc) {
            f4 w[4];
            #pragma unroll
            for (int g = 0; g < 4; ++g)
                w[g] = *(const f4*)&Wp[(size_t)(tx + 64 * g) * 64 + kc * 4];
            f4 a[4];
            #pragma unroll
            for (int kk = 0; kk < 4; ++kk)
                a[kk] = *(const f4*)&As[kc * 4 + kk][ty * 4];
            #pragma unroll
            for (int kk = 0; kk < 4; ++kk)
                #pragma unroll
                for (int rr = 0; rr < 4; ++rr) {
                    float av = a[kk][rr];
                    #pragma unroll
                    for (int g = 0; g < 4; ++g)
                        acc[rr][g] = fmaf(av, w[g][kk], acc[rr][g]);
                }
        }
    }

    float bsum[4];
    #pragma unroll
    for (int g = 0; g < 4; ++g) {
        float s = bh[tx + 64 * g];
        if (AHx) s += bxg[tx + 64 * g];
        if (Ax)  s += bx2[tx + 64 * g];
        bsum[g] = s;
    }
    #pragma unroll
    for (int rr = 0; rr < 4; ++rr) {
        const int r = row0 + ty * 4 + rr;
        float gv[4];
        #pragma unroll
        for (int g = 0; g < 4; ++g) gv[g] = acc[rr][g] + bsum[g];
        if (Ax) {
            int i = r >> 6, b = r & 63;
            float x0 = Ax[(size_t)i * 6144 + t * 128 + b * 2 + 0];
            float x1 = Ax[(size_t)i * 6144 + t * 128 + b * 2 + 1];
            #pragma unroll
            for (int g = 0; g < 4; ++g)
                gv[g] = fmaf(x0, Wx2[(tx + 64 * g) * 2 + 0],
                         fmaf(x1, Wx2[(tx + 64 * g) * 2 + 1], gv[g]));
        }
        float ig = 1.f / (1.f + expf(-gv[0]));
        float fg = 1.f / (1.f + expf(-gv[1]));
        float og = 1.f / (1.f + expf(-gv[2]));
        float gg = tanhf(gv[3]);
        size_t idx = (size_t)r * 64 + tx;
        float c = fg * Cst[idx] + ig * gg;
        Cst[idx] = c;
        Hout[idx] = og * tanhf(c);
    }
}

// ---------------- final projection: out[b][hor][i] = H1[i][b,:] . Wp[hor,:] + bp ----------------
__global__ __launch_bounds__(256) void proj_kernel(const float* __restrict__ H1,
                                                   const float* __restrict__ Wpj,
                                                   const float* __restrict__ bp,
                                                   float* __restrict__ out)
{
    int r = blockIdx.x * 256 + threadIdx.x;
    if (r >= 64000) return;
    int i = r >> 6, b = r & 63;
    f4 hv[16];
    #pragma unroll
    for (int q = 0; q < 16; ++q) hv[q] = *(const f4*)&H1[(size_t)r * 64 + q * 4];
    #pragma unroll
    for (int hor = 0; hor < 12; ++hor) {
        float s = bp[hor];
        #pragma unroll
        for (int q = 0; q < 16; ++q) {
            f4 w = *(const f4*)&Wpj[hor * 64 + q * 4];
            s = fmaf(hv[q][0], w[0], s);
            s = fmaf(hv[q][1], w[1], s);
            s = fmaf(hv[q][2], w[2], s);
            s = fmaf(hv[q][3], w[3], s);
        }
        out[(size_t)(b * 12 + hor) * 1000 + i] = s;
    }
}

extern "C" void kernel_launch(void* const* d_in, const int* in_sizes, int n_in,
                              void* d_out, int out_size, void* d_ws, size_t ws_size,
                              hipStream_t stream)
{
    const float* x   = (const float*)d_in[0];
    const float* E1  = (const float*)d_in[1];
    const float* E2  = (const float*)d_in[2];
    const float* Wx0 = (const float*)d_in[3];
    const float* bx0 = (const float*)d_in[4];
    const float* Wh0 = (const float*)d_in[5];
    const float* bh0 = (const float*)d_in[6];
    const float* Wx1 = (const float*)d_in[7];
    const float* bx1 = (const float*)d_in[8];
    const float* Wh1 = (const float*)d_in[9];
    const float* bh1 = (const float*)d_in[10];
    const float* Wp  = (const float*)d_in[11];
    const float* bp  = (const float*)d_in[12];
    float* out = (float*)d_out;
    float* ws  = (float*)d_ws;

    float* At  = ws + WS_AT;
    float* AX  = ws + WS_AX;
    float* H0  = ws + WS_H0;
    float* C0  = ws + WS_C0;
    float* H1  = ws + WS_H1;
    float* C1  = ws + WS_C1;
    float* AHa = ws + WS_AHA;
    float* AHb = ws + WS_AHB;
    float* Xr  = ws + WS_AHA;   // alias: only live before the T loop

    // zero H0,C0,H1,C1 (contiguous 16,384,000 floats)
    zero_kernel<<<16000, 256, 0, stream>>>(ws + WS_H0, 4096000);

    compute_A<<<1000, 256, 0, stream>>>(E1, E2, At);
    transpose_x<<<24000, 256, 0, stream>>>(x, Xr);
    // AX = A @ Xr   [1000][6144]
    gemm1000<<<dim3(16, 48), 256, 0, stream>>>(At, Xr, AX, 6144);

    for (int t = 0; t < 48; ++t) {
        // AH_a = A @ H0_prev
        gemm1000<<<dim3(16, 32), 256, 0, stream>>>(At, H0, AHa, 4096);
        // layer 0 gates + state update (in-place H0/C0)
        gates_kernel<<<4000, 256, 0, stream>>>(AHa, Wh0, bh0,
                                               nullptr, nullptr, nullptr,
                                               AX, Wx0, bx0, t,
                                               C0, H0);
        // AH_a = A @ H0_new ; AH_b = A @ H1_prev
        gemm1000<<<dim3(16, 32), 256, 0, stream>>>(At, H0, AHa, 4096);
        gemm1000<<<dim3(16, 32), 256, 0, stream>>>(At, H1, AHb, 4096);
        // layer 1 gates + state update
        gates_kernel<<<4000, 256, 0, stream>>>(AHb, Wh1, bh1,
                                               AHa, Wx1, bx1,
                                               nullptr, nullptr, nullptr, t,
                                               C1, H1);
    }
    proj_kernel<<<250, 256, 0, stream>>>(H1, Wp, bp, out);
    (void)in_sizes; (void)n_in; (void)out_size; (void)ws_size;
}

// Round 2
// 17859.157 us; speedup vs baseline: 2.4232x; 2.4232x over previous
//
#include <hip/hip_runtime.h>
#include <math.h>

typedef float f4 __attribute__((ext_vector_type(4)));

// ---------------- workspace layout (float offsets) ----------------
// At  : A transposed [j][i]            1,000,000
// AX  : A@x for all t [i][t*128+b*2+c] 6,144,000
// H0,C0,H1,C1 : [j][b*64+h]            4 x 4,096,000
// AHa : A@H0 (persists across steps)   4,096,000
// AHb : A@H1 (per-step scratch)        4,096,000
// W0T : Wh0^T  [64][256]                  16,384
// W1T : [Wx1;Wh1]^T  [128][256]           32,768
// Xr (transposed x) aliases AHa+AHb (dead after AX gemm; AHa zeroed after)
#define WS_AT   0
#define WS_AX   1000000
#define WS_H0   7144000
#define WS_C0   11240000
#define WS_H1   15336000
#define WS_C1   19432000
#define WS_AHA  23528000
#define WS_AHB  27624000
#define WS_W0T  31720000
#define WS_W1T  31736384

// ---------------- A = softmax(relu(E1 @ E2^T)) in fp64, store A^T ----------------
__global__ __launch_bounds__(256) void compute_A(const float* __restrict__ E1,
                                                 const float* __restrict__ E2,
                                                 float* __restrict__ At)
{
    __shared__ double z[1000];
    __shared__ double red[256];
    __shared__ double e1[16];
    const int i = blockIdx.x;
    const int tid = threadIdx.x;
    if (tid < 16) e1[tid] = (double)E1[i * 16 + tid];
    __syncthreads();
    double lmax = -1e300;
    for (int j = tid; j < 1000; j += 256) {
        double s = 0.0;
        #pragma unroll
        for (int c = 0; c < 16; ++c) s += e1[c] * (double)E2[j * 16 + c];
        if (s < 0.0) s = 0.0;              // relu
        z[j] = s;
        if (s > lmax) lmax = s;
    }
    red[tid] = lmax; __syncthreads();
    for (int off = 128; off > 0; off >>= 1) {
        if (tid < off) red[tid] = fmax(red[tid], red[tid + off]);
        __syncthreads();
    }
    const double zmax = red[0];
    __syncthreads();
    double lsum = 0.0;
    for (int j = tid; j < 1000; j += 256) {
        double e = exp(z[j] - zmax);
        z[j] = e;
        lsum += e;
    }
    red[tid] = lsum; __syncthreads();
    for (int off = 128; off > 0; off >>= 1) {
        if (tid < off) red[tid] += red[tid + off];
        __syncthreads();
    }
    const double inv = 1.0 / red[0];
    for (int j = tid; j < 1000; j += 256)
        At[(size_t)j * 1000 + i] = (float)(z[j] * inv);   // store transposed
}

// ---------------- x [B,T,N,C] -> Xr [j][t*128 + b*2 + c] ----------------
__global__ __launch_bounds__(256) void transpose_x(const float* __restrict__ x,
                                                   float* __restrict__ Xr)
{
    int o = blockIdx.x * 256 + threadIdx.x;
    if (o >= 6144000) return;
    int j = o / 6144;
    int r = o - j * 6144;
    int t = r >> 7;
    int q = r & 127;
    int b = q >> 1;
    int c = q & 1;
    Xr[o] = x[(((size_t)(b * 48 + t)) * 1000 + j) * 2 + c];
}

// ---------------- zero fill ----------------
__global__ __launch_bounds__(256) void zero_kernel(float* __restrict__ p, int n4)
{
    int i = blockIdx.x * 256 + threadIdx.x;
    if (i < n4) { f4 z = {0.f, 0.f, 0.f, 0.f}; ((f4*)p)[i] = z; }
}

// ---------------- weight transposes (once per launch) ----------------
__global__ __launch_bounds__(256) void prep_w(const float* __restrict__ Wh0,
                                              const float* __restrict__ Wx1,
                                              const float* __restrict__ Wh1,
                                              float* __restrict__ W0T,
                                              float* __restrict__ W1T)
{
    int idx = blockIdx.x * 256 + threadIdx.x;
    if (idx < 16384) {
        int k = idx >> 8, o = idx & 255;
        W0T[idx] = Wh0[o * 64 + k];
    }
    int j = idx - 16384;
    if (j >= 0 && j < 32768) {
        int k = j >> 8, o = j & 255;
        W1T[j] = (k < 64) ? Wx1[o * 64 + k] : Wh1[o * 64 + (k - 64)];
    }
}

// ---------------- C[1000][ncols] = A @ B ; A given transposed At[k][1000] ----------------
// BM=64 BN=128 BK=8, 256 threads, 4x8 micro-tile
__global__ __launch_bounds__(256) void gemm1000(const float* __restrict__ At,
                                                const float* __restrict__ B,
                                                float* __restrict__ C,
                                                int ncols)
{
    __shared__ float As[8][64];
    __shared__ float Bs[8][128];
    const int tid = threadIdx.x;
    const int tx = tid & 15;          // col group: cols tx*8 .. +7
    const int ty = tid >> 4;          // row group: rows ty*4 .. +3
    const int row0 = blockIdx.x * 64;
    const int col0 = blockIdx.y * 128;

    const int lm = tid & 63;
    const int lk = tid >> 6;          // 0..3  (k = lk, lk+4)
    const int bcol = tid & 127;
    const int bk = tid >> 7;          // 0..1  (k = bk*4 + kk)
    const bool arow_ok = (row0 + lm) < 1000;

    float acc[4][8];
    #pragma unroll
    for (int r = 0; r < 4; ++r)
        #pragma unroll
        for (int c = 0; c < 8; ++c) acc[r][c] = 0.f;

    for (int k0 = 0; k0 < 1000; k0 += 8) {
        float a0 = arow_ok ? At[(size_t)(k0 + lk) * 1000 + row0 + lm] : 0.f;
        float a1 = arow_ok ? At[(size_t)(k0 + lk + 4) * 1000 + row0 + lm] : 0.f;
        float bv[4];
        #pragma unroll
        for (int kk = 0; kk < 4; ++kk)
            bv[kk] = B[(size_t)(k0 + bk * 4 + kk) * ncols + col0 + bcol];
        __syncthreads();
        As[lk][lm] = a0;
        As[lk + 4][lm] = a1;
        #pragma unroll
        for (int kk = 0; kk < 4; ++kk) Bs[bk * 4 + kk][bcol] = bv[kk];
        __syncthreads();
        #pragma unroll
        for (int k = 0; k < 8; ++k) {
            f4 av = *(const f4*)&As[k][ty * 4];
            f4 b0 = *(const f4*)&Bs[k][tx * 8];
            f4 b1 = *(const f4*)&Bs[k][tx * 8 + 4];
            #pragma unroll
            for (int r = 0; r < 4; ++r) {
                float a = av[r];
                acc[r][0] = fmaf(a, b0[0], acc[r][0]);
                acc[r][1] = fmaf(a, b0[1], acc[r][1]);
                acc[r][2] = fmaf(a, b0[2], acc[r][2]);
                acc[r][3] = fmaf(a, b0[3], acc[r][3]);
                acc[r][4] = fmaf(a, b1[0], acc[r][4]);
                acc[r][5] = fmaf(a, b1[1], acc[r][5]);
                acc[r][6] = fmaf(a, b1[2], acc[r][6]);
                acc[r][7] = fmaf(a, b1[3], acc[r][7]);
            }
        }
    }
    #pragma unroll
    for (int r = 0; r < 4; ++r) {
        int row = row0 + ty * 4 + r;
        if (row < 1000) {
            f4 o0 = {acc[r][0], acc[r][1], acc[r][2], acc[r][3]};
            f4 o1 = {acc[r][4], acc[r][5], acc[r][6], acc[r][7]};
            *(f4*)&C[(size_t)row * ncols + col0 + tx * 8]     = o0;
            *(f4*)&C[(size_t)row * ncols + col0 + tx * 8 + 4] = o1;
        }
    }
}

// ---------------- gate GEMM v2: LDS-tiled, fused LSTM pointwise ----------------
// gates[r][gc] = sum_k AHcat[r][k] * WT[k][gc] + b1[gc] + b2[gc] (+ x-path)
// M=64000 rows (r=i*64+b), N=256 (gc=g*64+h), K=64 (pB=null) or 128.
// Block: 64 rows x 256 cols; 256 threads; micro-tile 4 rows x 4 gates x 4 h.
// tx=tid&15 -> h = tx*4..+3 ; ty=tid>>4 -> rows ty*4..+3.
__global__ __launch_bounds__(256) void gates_v2(
    const float* __restrict__ pA,   // AH source, k in [0,64)
    const float* __restrict__ pB,   // AH source, k in [64,128) (null -> K=64)
    const float* __restrict__ WT,   // [K][256]
    const float* __restrict__ b1, const float* __restrict__ b2,
    const float* __restrict__ AX,  const float* __restrict__ WxE,  // x-path (null if none)
    int t,
    float* __restrict__ Cst, float* __restrict__ Hout)
{
    __shared__ float As[32][65];      // [k][m], padded
    __shared__ float Bs[32 * 256];    // [k][gc]
    __shared__ float wx[512];         // Wx (layer0 epilogue), [gc][2]
    const int tid = threadIdx.x;
    const int tx = tid & 15;
    const int ty = tid >> 4;
    const int row0 = blockIdx.x * 64;
    const int mrow = tid >> 3;        // 0..31
    const int f4i  = tid & 7;

    if (WxE && tid < 128) ((f4*)wx)[tid] = ((const f4*)WxE)[tid];

    f4 acc[4][4];
    #pragma unroll
    for (int r = 0; r < 4; ++r)
        #pragma unroll
        for (int g = 0; g < 4; ++g) acc[r][g] = (f4){0.f, 0.f, 0.f, 0.f};

    const int nchunk = pB ? 4 : 2;
    for (int ch = 0; ch < nchunk; ++ch) {
        const float* src = (ch < 2) ? pA : pB;
        const int koff = (ch & 1) * 32;
        // prefetch to regs
        f4 av0 = *(const f4*)&src[(size_t)(row0 + mrow) * 64 + koff + f4i * 4];
        f4 av1 = *(const f4*)&src[(size_t)(row0 + mrow + 32) * 64 + koff + f4i * 4];
        const float* wsrc = WT + ch * 8192;
        f4 bv[8];
        #pragma unroll
        for (int r = 0; r < 8; ++r) bv[r] = *(const f4*)&wsrc[(tid + r * 256) * 4];
        __syncthreads();              // previous chunk fully consumed
        #pragma unroll
        for (int j = 0; j < 4; ++j) {
            As[f4i * 4 + j][mrow]      = av0[j];
            As[f4i * 4 + j][mrow + 32] = av1[j];
        }
        #pragma unroll
        for (int r = 0; r < 8; ++r) *(f4*)&Bs[(tid + r * 256) * 4] = bv[r];
        __syncthreads();
        #pragma unroll
        for (int k = 0; k < 32; ++k) {
            float a[4];
            #pragma unroll
            for (int rr = 0; rr < 4; ++rr) a[rr] = As[k][ty * 4 + rr];
            f4 bq[4];
            #pragma unroll
            for (int g = 0; g < 4; ++g) bq[g] = *(const f4*)&Bs[k * 256 + g * 64 + tx * 4];
            #pragma unroll
            for (int rr = 0; rr < 4; ++rr)
                #pragma unroll
                for (int g = 0; g < 4; ++g)
                    acc[rr][g] += a[rr] * bq[g];
        }
    }

    // bias
    f4 bb[4];
    #pragma unroll
    for (int g = 0; g < 4; ++g) {
        f4 v1 = *(const f4*)&b1[g * 64 + tx * 4];
        f4 v2 = *(const f4*)&b2[g * 64 + tx * 4];
        bb[g] = v1 + v2;
    }

    #pragma unroll
    for (int rr = 0; rr < 4; ++rr) {
        const int r = row0 + ty * 4 + rr;
        f4 gv[4];
        #pragma unroll
        for (int g = 0; g < 4; ++g) gv[g] = acc[rr][g] + bb[g];
        if (AX) {
            int ii = r >> 6, b = r & 63;
            float x0 = AX[(size_t)ii * 6144 + t * 128 + b * 2 + 0];
            float x1 = AX[(size_t)ii * 6144 + t * 128 + b * 2 + 1];
            #pragma unroll
            for (int g = 0; g < 4; ++g)
                #pragma unroll
                for (int hh = 0; hh < 4; ++hh) {
                    int gc = g * 64 + tx * 4 + hh;
                    gv[g][hh] = fmaf(x0, wx[gc * 2 + 0],
                                fmaf(x1, wx[gc * 2 + 1], gv[g][hh]));
                }
        }
        size_t base = (size_t)r * 64 + tx * 4;
        f4 cold = *(const f4*)&Cst[base];
        f4 cnew, hnew;
        #pragma unroll
        for (int hh = 0; hh < 4; ++hh) {
            float ig = 1.f / (1.f + expf(-gv[0][hh]));
            float fg = 1.f / (1.f + expf(-gv[1][hh]));
            float og = 1.f / (1.f + expf(-gv[2][hh]));
            float gg = tanhf(gv[3][hh]);
            float c  = fg * cold[hh] + ig * gg;
            cnew[hh] = c;
            hnew[hh] = og * tanhf(c);
        }
        *(f4*)&Cst[base]  = cnew;
        *(f4*)&Hout[base] = hnew;
    }
}

// ---------------- final projection: out[b][hor][i] = H1[i][b,:] . Wp[hor,:] + bp ----------------
__global__ __launch_bounds__(256) void proj_kernel(const float* __restrict__ H1,
                                                   const float* __restrict__ Wpj,
                                                   const float* __restrict__ bp,
                                                   float* __restrict__ out)
{
    int r = blockIdx.x * 256 + threadIdx.x;
    if (r >= 64000) return;
    int i = r >> 6, b = r & 63;
    f4 hv[16];
    #pragma unroll
    for (int q = 0; q < 16; ++q) hv[q] = *(const f4*)&H1[(size_t)r * 64 + q * 4];
    #pragma unroll
    for (int hor = 0; hor < 12; ++hor) {
        float s = bp[hor];
        #pragma unroll
        for (int q = 0; q < 16; ++q) {
            f4 w = *(const f4*)&Wpj[hor * 64 + q * 4];
            s = fmaf(hv[q][0], w[0], s);
            s = fmaf(hv[q][1], w[1], s);
            s = fmaf(hv[q][2], w[2], s);
            s = fmaf(hv[q][3], w[3], s);
        }
        out[(size_t)(b * 12 + hor) * 1000 + i] = s;
    }
}

extern "C" void kernel_launch(void* const* d_in, const int* in_sizes, int n_in,
                              void* d_out, int out_size, void* d_ws, size_t ws_size,
                              hipStream_t stream)
{
    const float* x   = (const float*)d_in[0];
    const float* E1  = (const float*)d_in[1];
    const float* E2  = (const float*)d_in[2];
    const float* Wx0 = (const float*)d_in[3];
    const float* bx0 = (const float*)d_in[4];
    const float* Wh0 = (const float*)d_in[5];
    const float* bh0 = (const float*)d_in[6];
    const float* Wx1 = (const float*)d_in[7];
    const float* bx1 = (const float*)d_in[8];
    const float* Wh1 = (const float*)d_in[9];
    const float* bh1 = (const float*)d_in[10];
    const float* Wp  = (const float*)d_in[11];
    const float* bp  = (const float*)d_in[12];
    float* out = (float*)d_out;
    float* ws  = (float*)d_ws;

    float* At  = ws + WS_AT;
    float* AX  = ws + WS_AX;
    float* H0  = ws + WS_H0;
    float* C0  = ws + WS_C0;
    float* H1  = ws + WS_H1;
    float* C1  = ws + WS_C1;
    float* AHa = ws + WS_AHA;
    float* AHb = ws + WS_AHB;
    float* W0T = ws + WS_W0T;
    float* W1T = ws + WS_W1T;
    float* Xr  = ws + WS_AHA;   // alias: dead after the AX gemm

    // zero H0,C0,H1,C1 (contiguous 16,384,000 floats)
    zero_kernel<<<16000, 256, 0, stream>>>(ws + WS_H0, 4096000);

    compute_A<<<1000, 256, 0, stream>>>(E1, E2, At);
    transpose_x<<<24000, 256, 0, stream>>>(x, Xr);
    // AX = A @ Xr   [1000][6144]
    gemm1000<<<dim3(16, 48), 256, 0, stream>>>(At, Xr, AX, 6144);
    // AHa must be zero at loop entry (A @ H0_init = 0); Xr now dead
    zero_kernel<<<4000, 256, 0, stream>>>(AHa, 1024000);
    prep_w<<<192, 256, 0, stream>>>(Wh0, Wx1, Wh1, W0T, W1T);

    for (int t = 0; t < 48; ++t) {
        // layer 0: gates = AHa @ Wh0^T + x-path; update H0,C0
        gates_v2<<<1000, 256, 0, stream>>>(AHa, nullptr, W0T, bh0, bx0,
                                           AX, Wx0, t, C0, H0);
        // AHa = A @ H0_new (also reused as next step's layer-0 input)
        gemm1000<<<dim3(16, 32), 256, 0, stream>>>(At, H0, AHa, 4096);
        // AHb = A @ H1_prev
        gemm1000<<<dim3(16, 32), 256, 0, stream>>>(At, H1, AHb, 4096);
        // layer 1: gates = AHa @ Wx1^T + AHb @ Wh1^T; update H1,C1
        gates_v2<<<1000, 256, 0, stream>>>(AHa, AHb, W1T, bh1, bx1,
                                           nullptr, nullptr, 0, C1, H1);
    }
    proj_kernel<<<250, 256, 0, stream>>>(H1, Wp, bp, out);
    (void)in_sizes; (void)n_in; (void)out_size; (void)ws_size;
}

// Round 4
// 10639.195 us; speedup vs baseline: 4.0677x; 1.6786x over previous
//
#include <hip/hip_runtime.h>
#include <math.h>

typedef float f4 __attribute__((ext_vector_type(4)));
typedef _Float16 h8 __attribute__((ext_vector_type(8)));

// ---------------- workspace layout (float offsets) ----------------
// AX   : A@x all t [i][t*128+b*2+c]   6,144,000
// AH0c : A@H0new fp32 [1024][4096]    4,194,304
// AH1c : A@H1prev fp32 [1024][4096]   4,194,304  (H0 fp32 [1000][4096] aliases here)
// H1F  : H1 fp32 [1000*64][64]        4,096,000
// C0,C1: cell state fp32              2 x 4,096,000
// HTh/HTl: H^T split f16 [4096][1024] 2 x 2,097,152 (f32 slots)
// Ah/Al: split f16 A [1024][1024]     2 x 524,288 (f32 slots)
// W0T [64][256], W1T [128][256]
// aliases: At fp32 [1000][1000] in C0 region; Xr in AH0c+AH1c region.
#define WS_AX    0
#define WS_AH0   6144000
#define WS_AH1   10338304
#define WS_H1F   14532608
#define WS_C0    18628608
#define WS_C1    22724608
#define WS_HTH   26820608
#define WS_HTL   28917760
#define WS_AH16  31014912
#define WS_AL16  31539200
#define WS_W0T   32063488
#define WS_W1T   32079872
// end = 32,112,640 floats = 128.45 MB (<= 128.84 MB proven in R2)

// ---------------- A = softmax(relu(E1 @ E2^T)) in fp64, store A^T ----------------
__global__ __launch_bounds__(256) void compute_A(const float* __restrict__ E1,
                                                 const float* __restrict__ E2,
                                                 float* __restrict__ At)
{
    __shared__ double z[1000];
    __shared__ double red[256];
    __shared__ double e1[16];
    const int i = blockIdx.x;
    const int tid = threadIdx.x;
    if (tid < 16) e1[tid] = (double)E1[i * 16 + tid];
    __syncthreads();
    double lmax = -1e300;
    for (int j = tid; j < 1000; j += 256) {
        double s = 0.0;
        #pragma unroll
        for (int c = 0; c < 16; ++c) s += e1[c] * (double)E2[j * 16 + c];
        if (s < 0.0) s = 0.0;
        z[j] = s;
        if (s > lmax) lmax = s;
    }
    red[tid] = lmax; __syncthreads();
    for (int off = 128; off > 0; off >>= 1) {
        if (tid < off) red[tid] = fmax(red[tid], red[tid + off]);
        __syncthreads();
    }
    const double zmax = red[0];
    __syncthreads();
    double lsum = 0.0;
    for (int j = tid; j < 1000; j += 256) {
        double e = exp(z[j] - zmax);
        z[j] = e;
        lsum += e;
    }
    red[tid] = lsum; __syncthreads();
    for (int off = 128; off > 0; off >>= 1) {
        if (tid < off) red[tid] += red[tid + off];
        __syncthreads();
    }
    const double inv = 1.0 / red[0];
    for (int j = tid; j < 1000; j += 256)
        At[(size_t)j * 1000 + i] = (float)(z[j] * inv);
}

// ---------------- x [B,T,N,C] -> Xr [j][t*128 + b*2 + c] ----------------
__global__ __launch_bounds__(256) void transpose_x(const float* __restrict__ x,
                                                   float* __restrict__ Xr)
{
    int o = blockIdx.x * 256 + threadIdx.x;
    if (o >= 6144000) return;
    int j = o / 6144;
    int r = o - j * 6144;
    int t = r >> 7;
    int q = r & 127;
    int b = q >> 1;
    int c = q & 1;
    Xr[o] = x[(((size_t)(b * 48 + t)) * 1000 + j) * 2 + c];
}

__global__ __launch_bounds__(256) void zero_kernel(float* __restrict__ p, int n4)
{
    int i = blockIdx.x * 256 + threadIdx.x;
    if (i < n4) { f4 z = {0.f, 0.f, 0.f, 0.f}; ((f4*)p)[i] = z; }
}

// ---------------- weight transposes (once) ----------------
__global__ __launch_bounds__(256) void prep_w(const float* __restrict__ Wh0,
                                              const float* __restrict__ Wx1,
                                              const float* __restrict__ Wh1,
                                              float* __restrict__ W0T,
                                              float* __restrict__ W1T)
{
    int idx = blockIdx.x * 256 + threadIdx.x;
    if (idx < 16384) {
        int k = idx >> 8, o = idx & 255;
        W0T[idx] = Wh0[o * 64 + k];
    }
    int j = idx - 16384;
    if (j >= 0 && j < 32768) {
        int k = j >> 8, o = j & 255;
        W1T[j] = (k < 64) ? Wx1[o * 64 + k] : Wh1[o * 64 + (k - 64)];
    }
}

// ---------------- split A^T fp32 -> Ah/Al f16 [m=1024][k=1024] ----------------
__global__ __launch_bounds__(256) void prep_A(const float* __restrict__ At,
                                              _Float16* __restrict__ Ahh,
                                              _Float16* __restrict__ All)
{
    int idx = blockIdx.x * 256 + threadIdx.x;   // 1,048,576
    int m = idx >> 10, k = idx & 1023;
    float v = (m < 1000 && k < 1000) ? At[(size_t)k * 1000 + m] : 0.f;
    _Float16 hi = (_Float16)v;
    Ahh[idx] = hi;
    All[idx] = (_Float16)((v - (float)hi) * 2048.f);
}

// ---------------- fp32 GEMM (used once for AX) ----------------
__global__ __launch_bounds__(256) void gemm1000(const float* __restrict__ At,
                                                const float* __restrict__ B,
                                                float* __restrict__ C,
                                                int ncols)
{
    __shared__ float As[8][64];
    __shared__ float Bs[8][128];
    const int tid = threadIdx.x;
    const int tx = tid & 15;
    const int ty = tid >> 4;
    const int row0 = blockIdx.x * 64;
    const int col0 = blockIdx.y * 128;
    const int lm = tid & 63;
    const int lk = tid >> 6;
    const int bcol = tid & 127;
    const int bk = tid >> 7;
    const bool arow_ok = (row0 + lm) < 1000;

    float acc[4][8];
    #pragma unroll
    for (int r = 0; r < 4; ++r)
        #pragma unroll
        for (int c = 0; c < 8; ++c) acc[r][c] = 0.f;

    for (int k0 = 0; k0 < 1000; k0 += 8) {
        float a0 = arow_ok ? At[(size_t)(k0 + lk) * 1000 + row0 + lm] : 0.f;
        float a1 = arow_ok ? At[(size_t)(k0 + lk + 4) * 1000 + row0 + lm] : 0.f;
        float bv[4];
        #pragma unroll
        for (int kk = 0; kk < 4; ++kk)
            bv[kk] = B[(size_t)(k0 + bk * 4 + kk) * ncols + col0 + bcol];
        __syncthreads();
        As[lk][lm] = a0;
        As[lk + 4][lm] = a1;
        #pragma unroll
        for (int kk = 0; kk < 4; ++kk) Bs[bk * 4 + kk][bcol] = bv[kk];
        __syncthreads();
        #pragma unroll
        for (int k = 0; k < 8; ++k) {
            f4 av = *(const f4*)&As[k][ty * 4];
            f4 b0 = *(const f4*)&Bs[k][tx * 8];
            f4 b1 = *(const f4*)&Bs[k][tx * 8 + 4];
            #pragma unroll
            for (int r = 0; r < 4; ++r) {
                float a = av[r];
                acc[r][0] = fmaf(a, b0[0], acc[r][0]);
                acc[r][1] = fmaf(a, b0[1], acc[r][1]);
                acc[r][2] = fmaf(a, b0[2], acc[r][2]);
                acc[r][3] = fmaf(a, b0[3], acc[r][3]);
                acc[r][4] = fmaf(a, b1[0], acc[r][4]);
                acc[r][5] = fmaf(a, b1[1], acc[r][5]);
                acc[r][6] = fmaf(a, b1[2], acc[r][6]);
                acc[r][7] = fmaf(a, b1[3], acc[r][7]);
            }
        }
    }
    #pragma unroll
    for (int r = 0; r < 4; ++r) {
        int row = row0 + ty * 4 + r;
        if (row < 1000) {
            f4 o0 = {acc[r][0], acc[r][1], acc[r][2], acc[r][3]};
            f4 o1 = {acc[r][4], acc[r][5], acc[r][6], acc[r][7]};
            *(f4*)&C[(size_t)row * ncols + col0 + tx * 8]     = o0;
            *(f4*)&C[(size_t)row * ncols + col0 + tx * 8 + 4] = o1;
        }
    }
}

// ---------------- H fp32 [1000 nodes][4096] -> HT split f16 [4096][1024] ----------------
__global__ __launch_bounds__(256) void transpose_split(const float* __restrict__ H,
                                                       _Float16* __restrict__ HTh,
                                                       _Float16* __restrict__ HTl)
{
    __shared__ float tile[32][33];
    const int tid = threadIdx.x;
    const int tx = tid & 31;
    const int ty = tid >> 5;            // 0..7
    const int n0 = blockIdx.x * 32;     // 128 n-tiles
    const int k0 = blockIdx.y * 32;     // 32 k-tiles
    #pragma unroll
    for (int j = 0; j < 4; ++j) {
        int k = k0 + ty * 4 + j;
        tile[ty * 4 + j][tx] = (k < 1000) ? H[(size_t)k * 4096 + n0 + tx] : 0.f;
    }
    __syncthreads();
    #pragma unroll
    for (int j = 0; j < 4; ++j) {
        int n = n0 + ty * 4 + j;
        float v = tile[tx][ty * 4 + j];
        _Float16 hi = (_Float16)v;
        size_t o = (size_t)n * 1024 + k0 + tx;
        HTh[o] = hi;
        HTl[o] = (_Float16)((v - (float)hi) * 2048.f);
    }
}

// ---------------- MFMA split-f16 GEMM: C[1024][4096] = A @ HT^T ----------------
// A [1024][1024] f16 (hi,lo), HT [4096][1024] f16 (hi,lo) -- both row-major-by-K.
// BM=128 BN=128 BK=32; 256 thr = 4 waves 2x2; wave tile 64x64 = 4x4 frags 16x16x32.
// Frags: 8 consecutive k per lane (row = lane&15, k = (lane>>4)*8 + i) -- ladder-verified.
__global__ __launch_bounds__(256) void gemm_ah(
    const _Float16* __restrict__ Ahg, const _Float16* __restrict__ Alg,
    const _Float16* __restrict__ Bhg, const _Float16* __restrict__ Blg,
    float* __restrict__ Cout)
{
    __shared__ __align__(16) _Float16 Ahs[128 * 40];
    __shared__ __align__(16) _Float16 Als[128 * 40];
    __shared__ __align__(16) _Float16 Bhs[128 * 40];
    __shared__ __align__(16) _Float16 Bls[128 * 40];
    const int tid = threadIdx.x;
    const int lane = tid & 63;
    const int w = tid >> 6;
    const int wr = w >> 1, wc = w & 1;
    const int g = lane >> 4, l15 = lane & 15;
    const int m0 = blockIdx.x * 128, n0 = blockIdx.y * 128;
    const int srow = tid >> 2;          // 0..63
    const int scol = (tid & 3) * 8;     // f16 col 0,8,16,24

    f4 acc0[4][4], acc1[4][4];
    #pragma unroll
    for (int a = 0; a < 4; ++a)
        #pragma unroll
        for (int b = 0; b < 4; ++b) {
            acc0[a][b] = (f4){0.f, 0.f, 0.f, 0.f};
            acc1[a][b] = (f4){0.f, 0.f, 0.f, 0.f};
        }

    for (int ks = 0; ks < 32; ++ks) {
        const int kb = ks * 32 + scol;
        f4 va[2], vl[2], vbh[2], vbl[2];
        #pragma unroll
        for (int s = 0; s < 2; ++s) {
            const size_t ga = (size_t)(m0 + s * 64 + srow) * 1024 + kb;
            const size_t gb = (size_t)(n0 + s * 64 + srow) * 1024 + kb;
            va[s]  = *(const f4*)&Ahg[ga];
            vl[s]  = *(const f4*)&Alg[ga];
            vbh[s] = *(const f4*)&Bhg[gb];
            vbl[s] = *(const f4*)&Blg[gb];
        }
        __syncthreads();                 // prev iter's frag reads complete
        #pragma unroll
        for (int s = 0; s < 2; ++s) {
            const int lo = (s * 64 + srow) * 40 + scol;
            *(f4*)&Ahs[lo] = va[s];
            *(f4*)&Als[lo] = vl[s];
            *(f4*)&Bhs[lo] = vbh[s];
            *(f4*)&Bls[lo] = vbl[s];
        }
        __syncthreads();                 // tiles visible

        h8 fa[4], fl[4];
        #pragma unroll
        for (int mf = 0; mf < 4; ++mf) {
            const int ao = (wr * 64 + mf * 16 + l15) * 40 + g * 8;
            fa[mf] = *(const h8*)&Ahs[ao];
            fl[mf] = *(const h8*)&Als[ao];
        }
        #pragma unroll
        for (int nf = 0; nf < 4; ++nf) {
            const int bo = (wc * 64 + nf * 16 + l15) * 40 + g * 8;
            const h8 bh = *(const h8*)&Bhs[bo];
            const h8 bl = *(const h8*)&Bls[bo];
            #pragma unroll
            for (int mf = 0; mf < 4; ++mf) {
                acc0[mf][nf] = __builtin_amdgcn_mfma_f32_16x16x32_f16(fa[mf], bh, acc0[mf][nf], 0, 0, 0);
                acc1[mf][nf] = __builtin_amdgcn_mfma_f32_16x16x32_f16(fa[mf], bl, acc1[mf][nf], 0, 0, 0);
                acc1[mf][nf] = __builtin_amdgcn_mfma_f32_16x16x32_f16(fl[mf], bh, acc1[mf][nf], 0, 0, 0);
            }
        }
    }

    // C/D layout (m89-verified): col = lane&15, row = (lane>>4)*4 + e
    #pragma unroll
    for (int mf = 0; mf < 4; ++mf)
        #pragma unroll
        for (int nf = 0; nf < 4; ++nf) {
            const int row = m0 + wr * 64 + mf * 16 + g * 4;
            const int col = n0 + wc * 64 + nf * 16 + l15;
            #pragma unroll
            for (int e = 0; e < 4; ++e)
                Cout[(size_t)(row + e) * 4096 + col] =
                    acc0[mf][nf][e] + acc1[mf][nf][e] * (1.f / 2048.f);
        }
}

// ---------------- gate GEMM (LDS-tiled) + LSTM pointwise ----------------
// Block: 64 rows (r = row0..row0+63, r = i*64+b), 256 cols (gc = g*64+h), K=64 or 128.
// AH buffers are [1024 nodes][4096] fp32 == [64000+][64] row-major (i*4096+b*64 = r*64).
__global__ __launch_bounds__(256) void gates_v2(
    const float* __restrict__ pA,   // k 0..63
    const float* __restrict__ pB,   // k 64..127 (null -> K=64)
    const float* __restrict__ WT,   // [K][256]
    const float* __restrict__ b1, const float* __restrict__ b2,
    const float* __restrict__ AX, const float* __restrict__ WxE,
    int t,
    float* __restrict__ Cst, float* __restrict__ Hout)
{
    __shared__ float As[32][65];
    __shared__ float Bs[32 * 256];
    __shared__ float wx[512];
    const int tid = threadIdx.x;
    const int tx = tid & 15;
    const int ty = tid >> 4;            // 0..15 -> rows ty*4..+3 (64 rows/block)
    const int row0 = blockIdx.x * 64;
    const int mrow = tid >> 3;          // 0..31
    const int f4i  = tid & 7;

    if (WxE && tid < 128) ((f4*)wx)[tid] = ((const f4*)WxE)[tid];

    f4 acc[4][4];
    #pragma unroll
    for (int r = 0; r < 4; ++r)
        #pragma unroll
        for (int gq = 0; gq < 4; ++gq) acc[r][gq] = (f4){0.f, 0.f, 0.f, 0.f};

    const int nchunk = pB ? 4 : 2;
    for (int ch = 0; ch < nchunk; ++ch) {
        const float* src = (ch < 2) ? pA : pB;
        const int koff = (ch & 1) * 32;
        f4 av0 = *(const f4*)&src[(size_t)(row0 + mrow) * 64 + koff + f4i * 4];
        f4 av1 = *(const f4*)&src[(size_t)(row0 + mrow + 32) * 64 + koff + f4i * 4];
        const float* wsrc = WT + ch * 8192;
        f4 bv[8];
        #pragma unroll
        for (int r = 0; r < 8; ++r) bv[r] = *(const f4*)&wsrc[(tid + r * 256) * 4];
        __syncthreads();
        #pragma unroll
        for (int j = 0; j < 4; ++j) {
            As[f4i * 4 + j][mrow]      = av0[j];
            As[f4i * 4 + j][mrow + 32] = av1[j];
        }
        #pragma unroll
        for (int r = 0; r < 8; ++r) *(f4*)&Bs[(tid + r * 256) * 4] = bv[r];
        __syncthreads();
        #pragma unroll
        for (int k = 0; k < 32; ++k) {
            float a[4];
            #pragma unroll
            for (int rr = 0; rr < 4; ++rr) a[rr] = As[k][ty * 4 + rr];
            f4 bq[4];
            #pragma unroll
            for (int gq = 0; gq < 4; ++gq) bq[gq] = *(const f4*)&Bs[k * 256 + gq * 64 + tx * 4];
            #pragma unroll
            for (int rr = 0; rr < 4; ++rr)
                #pragma unroll
                for (int gq = 0; gq < 4; ++gq)
                    acc[rr][gq] += a[rr] * bq[gq];
        }
    }

    f4 bb[4];
    #pragma unroll
    for (int gq = 0; gq < 4; ++gq) {
        f4 v1 = *(const f4*)&b1[gq * 64 + tx * 4];
        f4 v2 = *(const f4*)&b2[gq * 64 + tx * 4];
        bb[gq] = v1 + v2;
    }

    #pragma unroll
    for (int rr = 0; rr < 4; ++rr) {
        const int r = row0 + ty * 4 + rr;
        f4 gv[4];
        #pragma unroll
        for (int gq = 0; gq < 4; ++gq) gv[gq] = acc[rr][gq] + bb[gq];
        if (AX) {
            int ii = r >> 6, b = r & 63;
            float x0 = AX[(size_t)ii * 6144 + t * 128 + b * 2 + 0];
            float x1 = AX[(size_t)ii * 6144 + t * 128 + b * 2 + 1];
            #pragma unroll
            for (int gq = 0; gq < 4; ++gq)
                #pragma unroll
                for (int hh = 0; hh < 4; ++hh) {
                    int gc = gq * 64 + tx * 4 + hh;
                    gv[gq][hh] = fmaf(x0, wx[gc * 2 + 0],
                                 fmaf(x1, wx[gc * 2 + 1], gv[gq][hh]));
                }
        }
        size_t base = (size_t)r * 64 + tx * 4;
        f4 cold = *(const f4*)&Cst[base];
        f4 cnew, hnew;
        #pragma unroll
        for (int hh = 0; hh < 4; ++hh) {
            float ig = 1.f / (1.f + expf(-gv[0][hh]));
            float fg = 1.f / (1.f + expf(-gv[1][hh]));
            float og = 1.f / (1.f + expf(-gv[2][hh]));
            float gg = tanhf(gv[3][hh]);
            float c  = fg * cold[hh] + ig * gg;
            cnew[hh] = c;
            hnew[hh] = og * tanhf(c);
        }
        *(f4*)&Cst[base]  = cnew;
        *(f4*)&Hout[base] = hnew;
    }
}

// ---------------- final projection ----------------
__global__ __launch_bounds__(256) void proj_kernel(const float* __restrict__ H1,
                                                   const float* __restrict__ Wpj,
                                                   const float* __restrict__ bp,
                                                   float* __restrict__ out)
{
    int r = blockIdx.x * 256 + threadIdx.x;
    if (r >= 64000) return;
    int i = r >> 6, b = r & 63;
    f4 hv[16];
    #pragma unroll
    for (int q = 0; q < 16; ++q) hv[q] = *(const f4*)&H1[(size_t)r * 64 + q * 4];
    #pragma unroll
    for (int hor = 0; hor < 12; ++hor) {
        float s = bp[hor];
        #pragma unroll
        for (int q = 0; q < 16; ++q) {
            f4 w = *(const f4*)&Wpj[hor * 64 + q * 4];
            s = fmaf(hv[q][0], w[0], s);
            s = fmaf(hv[q][1], w[1], s);
            s = fmaf(hv[q][2], w[2], s);
            s = fmaf(hv[q][3], w[3], s);
        }
        out[(size_t)(b * 12 + hor) * 1000 + i] = s;
    }
}

extern "C" void kernel_launch(void* const* d_in, const int* in_sizes, int n_in,
                              void* d_out, int out_size, void* d_ws, size_t ws_size,
                              hipStream_t stream)
{
    const float* x   = (const float*)d_in[0];
    const float* E1  = (const float*)d_in[1];
    const float* E2  = (const float*)d_in[2];
    const float* Wx0 = (const float*)d_in[3];
    const float* bx0 = (const float*)d_in[4];
    const float* Wh0 = (const float*)d_in[5];
    const float* bh0 = (const float*)d_in[6];
    const float* Wx1 = (const float*)d_in[7];
    const float* bx1 = (const float*)d_in[8];
    const float* Wh1 = (const float*)d_in[9];
    const float* bh1 = (const float*)d_in[10];
    const float* Wp  = (const float*)d_in[11];
    const float* bp  = (const float*)d_in[12];
    float* out = (float*)d_out;
    float* ws  = (float*)d_ws;

    float*    AX   = ws + WS_AX;
    float*    AH0c = ws + WS_AH0;
    float*    AH1c = ws + WS_AH1;
    float*    H1F  = ws + WS_H1F;
    float*    C0   = ws + WS_C0;
    float*    C1   = ws + WS_C1;
    _Float16* HTh  = (_Float16*)(ws + WS_HTH);
    _Float16* HTl  = (_Float16*)(ws + WS_HTL);
    _Float16* Ah   = (_Float16*)(ws + WS_AH16);
    _Float16* Al   = (_Float16*)(ws + WS_AL16);
    float*    W0T  = ws + WS_W0T;
    float*    W1T  = ws + WS_W1T;
    float*    At   = ws + WS_C0;    // alias: dead before C0 zeroed
    float*    Xr   = ws + WS_AH0;   // alias: dead before AH0c zeroed
    float*    H0F  = ws + WS_AH1;   // alias: H0 fp32 lives in AH1c between gates0 and gemm1

    compute_A<<<1000, 256, 0, stream>>>(E1, E2, At);
    transpose_x<<<24000, 256, 0, stream>>>(x, Xr);
    gemm1000<<<dim3(16, 48), 256, 0, stream>>>(At, Xr, AX, 6144);   // AX = A @ Xr
    prep_w<<<192, 256, 0, stream>>>(Wh0, Wx1, Wh1, W0T, W1T);
    prep_A<<<4096, 256, 0, stream>>>(At, Ah, Al);
    zero_kernel<<<8000, 256, 0, stream>>>(ws + WS_C0, 2048000);     // C0,C1 (kills At)
    zero_kernel<<<4096, 256, 0, stream>>>(AH0c, 1048576);           // AH0c (kills Xr head)
    zero_kernel<<<4000, 256, 0, stream>>>(H1F, 1024000);            // H1

    for (int t = 0; t < 48; ++t) {
        // layer 0: gates from A@H0prev (AH0c) + x-path -> H0 fp32 (in AH1c region)
        gates_v2<<<1000, 256, 0, stream>>>(AH0c, nullptr, W0T, bh0, bx0,
                                           AX, Wx0, t, C0, H0F);
        // AH0c = A @ H0new
        transpose_split<<<dim3(128, 32), 256, 0, stream>>>(H0F, HTh, HTl);
        gemm_ah<<<dim3(8, 32), 256, 0, stream>>>(Ah, Al, HTh, HTl, AH0c);
        // AH1c = A @ H1prev (overwrites H0 alias -- H0 already consumed)
        transpose_split<<<dim3(128, 32), 256, 0, stream>>>(H1F, HTh, HTl);
        gemm_ah<<<dim3(8, 32), 256, 0, stream>>>(Ah, Al, HTh, HTl, AH1c);
        // layer 1: gates = (A@H0new)Wx1^T + (A@H1prev)Wh1^T -> H1 fp32
        gates_v2<<<1000, 256, 0, stream>>>(AH0c, AH1c, W1T, bh1, bx1,
                                           nullptr, nullptr, 0, C1, H1F);
    }
    proj_kernel<<<250, 256, 0, stream>>>(H1F, Wp, bp, out);
    (void)in_sizes; (void)n_in; (void)out_size; (void)ws_size;
}